// Round 1
// baseline (310.974 us; speedup 1.0000x reference)
//
#include <hip/hip_runtime.h>
#include <math.h>

typedef unsigned long long u64;
typedef unsigned int u32;
#define INF64 0xFFFFFFFFFFFFFFFFULL
#define FBIG 3.3e38f
#define KSEL 20
#define QT   32      // queries per block = MFMA N dim
#define CNK  16      // chunks per side
#define CAP  256     // survivor buffer per query (typ ~64 with 21-of-1024 bound)
#define PREFT 4      // prefix tiles per wave (8 waves * 4 * 32 rows = 1024-row sample)
#define DEPS 0.5f    // 2*eps bound slack; worst-case |approx-exact| d2 err ~0.18
#define NTHR 512

typedef __bf16 bf16x8 __attribute__((ext_vector_type(8)));
typedef float  f32x16 __attribute__((ext_vector_type(16)));
typedef unsigned int uint4e __attribute__((ext_vector_type(4)));

static __device__ __forceinline__ u64 umin64(u64 a, u64 b) { return a < b ? a : b; }
static __device__ __forceinline__ u32 asu(float f) { return __builtin_bit_cast(u32, f); }
static __device__ __forceinline__ float trunchi(u32 u) { return __builtin_bit_cast(float, u & 0xffff0000u); }
#define PERM2(a,b) __builtin_amdgcn_perm((a),(b),0x07060302u)
static __device__ __forceinline__ bf16x8 mk8(u32 a, u32 b, u32 c, u32 d) {
    uint4e t = {a, b, c, d};
    return __builtin_bit_cast(bf16x8, t);
}
static __device__ __forceinline__ f32x16 zero16() {
    f32x16 z = {0.f,0.f,0.f,0.f,0.f,0.f,0.f,0.f,0.f,0.f,0.f,0.f,0.f,0.f,0.f,0.f};
    return z;
}

static __device__ __forceinline__ float dot16(
    float4 a0, float4 a1, float4 a2, float4 a3,
    float4 b0, float4 b1, float4 b2, float4 b3)
{
    float d = 0.f;
    d = fmaf(a0.x, b0.x, d); d = fmaf(a0.y, b0.y, d);
    d = fmaf(a0.z, b0.z, d); d = fmaf(a0.w, b0.w, d);
    d = fmaf(a1.x, b1.x, d); d = fmaf(a1.y, b1.y, d);
    d = fmaf(a1.z, b1.z, d); d = fmaf(a1.w, b1.w, d);
    d = fmaf(a2.x, b2.x, d); d = fmaf(a2.y, b2.y, d);
    d = fmaf(a2.z, b2.z, d); d = fmaf(a2.w, b2.w, d);
    d = fmaf(a3.x, b3.x, d); d = fmaf(a3.y, b3.y, d);
    d = fmaf(a3.z, b3.z, d); d = fmaf(a3.w, b3.w, d);
    return d;
}

// split 8 floats into bf16-hi (truncation) and bf16-lo (residual, truncated) frags
static __device__ __forceinline__ void cvt_hilo(float4 f0, float4 f1, bf16x8& hi, bf16x8& lo) {
    u32 u0=asu(f0.x),u1=asu(f0.y),u2=asu(f0.z),u3=asu(f0.w);
    u32 u4=asu(f1.x),u5=asu(f1.y),u6=asu(f1.z),u7=asu(f1.w);
    hi = mk8(PERM2(u1,u0), PERM2(u3,u2), PERM2(u5,u4), PERM2(u7,u6));
    u32 w0=asu(f0.x-trunchi(u0)), w1=asu(f0.y-trunchi(u1));
    u32 w2=asu(f0.z-trunchi(u2)), w3=asu(f0.w-trunchi(u3));
    u32 w4=asu(f1.x-trunchi(u4)), w5=asu(f1.y-trunchi(u5));
    u32 w6=asu(f1.z-trunchi(u6)), w7=asu(f1.w-trunchi(u7));
    lo = mk8(PERM2(w1,w0), PERM2(w3,w2), PERM2(w5,w4), PERM2(w7,w6));
}

// one 32-row x 32-query tile: qe[row][q] ~= Q.E^T via 3 chained MFMAs (hi*hi+hi*lo+lo*hi)
static __device__ __forceinline__ f32x16 tile_qe(
    const float* __restrict__ embS, int base, int col, int kb, int N,
    bf16x8 B1, bf16x8 B2)
{
    int row = base + col;
    row = min(row, N - 1);                       // OOB rows: ne-pad (FBIG) filters them
    const float4* ep = (const float4*)(embS + (size_t)row * 16 + kb * 8);
    float4 f0 = ep[0], f1 = ep[1];
    bf16x8 A1, A2;
    cvt_hilo(f0, f1, A1, A2);
    f32x16 acc = zero16();
    acc = __builtin_amdgcn_mfma_f32_32x32x16_bf16(A1, B1, acc, 0, 0, 0);
    acc = __builtin_amdgcn_mfma_f32_32x32x16_bf16(A1, B2, acc, 0, 0, 0);
    acc = __builtin_amdgcn_mfma_f32_32x32x16_bf16(A2, B1, acc, 0, 0, 0);
    return acc;
}

// per-row squared norms, padded with FBIG past N (self-filtering ragged tiles)
__global__ __launch_bounds__(256) void norm_kernel(
    const float* __restrict__ emb0, const float* __restrict__ emb1,
    float* __restrict__ neBuf, int N, int npad)
{
    const int j = blockIdx.x * 256 + threadIdx.x;
    const float* __restrict__ e = blockIdx.y ? emb1 : emb0;
    float* __restrict__ o = neBuf + (size_t)blockIdx.y * npad;
    float v = FBIG;
    if (j < N) {
        const float4* p = (const float4*)(e + (size_t)j * 16);
        float4 e0=p[0],e1=p[1],e2=p[2],e3=p[3];
        v = dot16(e0,e1,e2,e3, e0,e1,e2,e3);
    }
    if (j < npad) o[j] = v;
}

// Kernel A: per (side, 32-query tile, chunk). MFMA approximate filter + exact refine.
// D layout (m74/m101): col = lane&31 (query), row = (r&3) + 8*(r>>2) + 4*(lane>>5).
__global__ __launch_bounds__(NTHR, 4) void knn_scan_kernel(
    const float* __restrict__ emb0, const float* __restrict__ emb1,
    const int* __restrict__ idx0, const int* __restrict__ idx1,
    const float* __restrict__ neBuf,
    u64* __restrict__ chunkTop, int N, int B, int chlen)
{
    const int tid  = threadIdx.x;
    const int lane = tid & 63;
    const int wv   = tid >> 6;          // 0..7
    const int col  = lane & 31;         // query column
    const int kb   = lane >> 5;         // k-half / row-group bit
    const int bx   = blockIdx.x;
    const int xcd  = bx & 7;            // XCD swizzle: even XCDs side 0, odd side 1
    const int s    = xcd & 1;
    const int t_   = (bx >> 3) * 4 + (xcd >> 1);
    const int c    = t_ & (CNK - 1);
    const int qt   = t_ >> 4;
    const int qbase = qt * QT;
    const int jbeg = c * chlen;
    const int tpc  = chlen >> 5;        // 32-row tiles per chunk
    const int npad = chlen * CNK;

    const float* __restrict__ embS = s ? emb1 : emb0;
    const int*   __restrict__ idxp = s ? idx1 : idx0;
    const float* __restrict__ neS  = neBuf + (size_t)s * npad;

    __shared__ float Qs[QT][16];
    __shared__ float naS[QT];
    __shared__ int   sq[QT];
    __shared__ int   scnt[QT];
    __shared__ float sthr[QT];
    __shared__ float sMin[QT][32];
    __shared__ u32   sbuf[QT][CAP];

    if (tid < QT) { sq[tid] = idxp[qbase + tid]; scnt[tid] = 0; }
    __syncthreads();
    if (tid < 128) {
        int q = tid >> 2, part = tid & 3;
        ((float4*)(&Qs[q][0]))[part] = ((const float4*)(embS + (size_t)sq[q] * 16))[part];
    }
    __syncthreads();
    if (tid < QT) {
        const float4* qp = (const float4*)(&Qs[tid][0]);
        float4 a0=qp[0],a1=qp[1],a2=qp[2],a3=qp[3];
        naS[tid] = dot16(a0,a1,a2,a3, a0,a1,a2,a3);
    }
    // B fragments: this lane's 8 k-elements of query col (hi and lo parts)
    bf16x8 B1, B2;
    {
        const float4* qp = (const float4*)(&Qs[col][kb * 8]);
        float4 f0 = qp[0], f1 = qp[1];
        cvt_hilo(f0, f1, B1, B2);
    }
    __syncthreads();

    const float na_l  = naS[col];
    const int   self_l = sq[col];

    // ---- prefix sample: 2-smallest approx-d2 per lane over 4 tiles (128 rows/lane)
    float m0v = FBIG, m1v = FBIG;
#define PINS(r, nef) { float v_ = fmaf(acc[r], -2.f, na_l + (nef)); \
    float t1_ = fminf(m1v, fmaxf(m0v, v_)); m0v = fminf(m0v, v_); m1v = t1_; }
    for (int pt = 0; pt < PREFT; ++pt) {
        const int t = wv + pt * 8;
        const int base = jbeg + t * 32;
        const float4* np_ = (const float4*)(neS + base + kb * 4);
        float4 n0 = np_[0], n1 = np_[2], n2 = np_[4], n3 = np_[6];
        f32x16 acc = tile_qe(embS, base, col, kb, N, B1, B2);
        PINS(0,n0.x)  PINS(1,n0.y)  PINS(2,n0.z)  PINS(3,n0.w)
        PINS(4,n1.x)  PINS(5,n1.y)  PINS(6,n1.z)  PINS(7,n1.w)
        PINS(8,n2.x)  PINS(9,n2.y)  PINS(10,n2.z) PINS(11,n2.w)
        PINS(12,n3.x) PINS(13,n3.y) PINS(14,n3.z) PINS(15,n3.w)
    }
#undef PINS
    sMin[col][(wv * 2 + kb) * 2 + 0] = m0v;
    sMin[col][(wv * 2 + kb) * 2 + 1] = m1v;
    __syncthreads();

    // ---- wave wv: 21st-smallest of its 4 queries' 32 sampled mins = filter bound
    for (int qq = 0; qq < 4; ++qq) {
        const int q = wv * 4 + qq;
        float v = (lane < 32) ? sMin[q][lane] : FBIG;
        float gm = 0.f;
        for (int r = 0; r < KSEL + 1; ++r) {
            float cm = v;
#pragma unroll
            for (int o = 32; o; o >>= 1) cm = fminf(cm, __shfl_xor(cm, o, 64));
            gm = cm;
            if (v == gm) v = FBIG;
        }
        if (lane == 0) sthr[q] = gm + DEPS;
    }
    __syncthreads();
    const float thr_l = sthr[col];

    // ---- main filtered scan over all tiles of the chunk
#define EPI(r, nef) { float ad_ = fmaf(acc[r], -2.f, na_l + (nef)); \
    if (ad_ <= thr_l) msk |= (1u << (r)); }
    for (int t = wv; t < tpc; t += 8) {
        const int base = jbeg + t * 32;
        const float4* np_ = (const float4*)(neS + base + kb * 4);
        float4 n0 = np_[0], n1 = np_[2], n2 = np_[4], n3 = np_[6];
        f32x16 acc = tile_qe(embS, base, col, kb, N, B1, B2);
        u32 msk = 0;
        EPI(0,n0.x)  EPI(1,n0.y)  EPI(2,n0.z)  EPI(3,n0.w)
        EPI(4,n1.x)  EPI(5,n1.y)  EPI(6,n1.z)  EPI(7,n1.w)
        EPI(8,n2.x)  EPI(9,n2.y)  EPI(10,n2.z) EPI(11,n2.w)
        EPI(12,n3.x) EPI(13,n3.y) EPI(14,n3.z) EPI(15,n3.w)
        if (msk) {
#pragma unroll
            for (int r = 0; r < 16; ++r) if (msk & (1u << r)) {
                int j = base + (r & 3) + 8 * (r >> 2) + 4 * kb;
                if (j != self_l) {
                    int sl = atomicAdd(&scnt[col], 1);
                    if (sl < CAP) sbuf[col][sl] = (u32)j;
                }
            }
        }
    }
#undef EPI
    __syncthreads();

    // ---- exact refine (bit-identical fp32 dot16 path) + top-20 per query
    for (int qq = 0; qq < 4; ++qq) {
        const int q = wv * 4 + qq;
        const int M = min(scnt[q], CAP);
        const float4* qp = (const float4*)(&Qs[q][0]);
        const float4 q0=qp[0], q1=qp[1], q2=qp[2], q3=qp[3];
        const float naq = naS[q];
        auto rk = [&](int i) -> u64 {
            int j = (int)sbuf[q][i];
            const float4* p = (const float4*)(embS + (size_t)j * 16);
            float4 e0=p[0],e1=p[1],e2=p[2],e3=p[3];
            float ne_ = dot16(e0,e1,e2,e3, e0,e1,e2,e3);
            float qe  = dot16(q0,q1,q2,q3, e0,e1,e2,e3);
            float dd  = fmaxf(fmaf(qe, -2.f, naq + ne_), 0.f);
            return ((u64)asu(dd) << 32) | (u32)j;
        };
        u64 k0 = INF64, k1 = INF64, k2 = INF64, k3 = INF64;
        if (lane < M)       k0 = rk(lane);
        if (lane + 64 < M)  k1 = rk(lane + 64);
        if (lane + 128 < M) k2 = rk(lane + 128);
        if (lane + 192 < M) k3 = rk(lane + 192);
        u64 keep = INF64;
        if (M <= 128) {
            for (int r = 0; r < KSEL; ++r) {
                u64 cm = umin64(k0, k1);
#pragma unroll
                for (int o = 32; o; o >>= 1) cm = umin64(cm, __shfl_xor(cm, o, 64));
                if (k0 == cm) k0 = INF64;
                if (k1 == cm) k1 = INF64;
                if (lane == r) keep = cm;
            }
        } else {
            for (int r = 0; r < KSEL; ++r) {
                u64 cm = umin64(umin64(k0, k1), umin64(k2, k3));
#pragma unroll
                for (int o = 32; o; o >>= 1) cm = umin64(cm, __shfl_xor(cm, o, 64));
                if (k0 == cm) k0 = INF64;
                if (k1 == cm) k1 = INF64;
                if (k2 == cm) k2 = INF64;
                if (k3 == cm) k3 = INF64;
                if (lane == r) keep = cm;
            }
        }
        if (lane < KSEL)
            chunkTop[((size_t)(s * B + qbase + q) * CNK + c) * KSEL + lane] = keep;
    }
}

// Kernel B: per row b: wave s merges its side's CNK chunk-top-20s -> top-20,
// gathers rctx, computes f1/f2/f3; then lanes 0-63 run the fused MLP.
__global__ __launch_bounds__(128) void merge_mlp_kernel(
    const u64* __restrict__ chunkTop,
    const float* __restrict__ rctx0, const float* __restrict__ rctx1,
    const float* __restrict__ mean_in, const float* __restrict__ std_in,
    const float* __restrict__ W1, const float* __restrict__ b1,
    const float* __restrict__ Wm, const float* __restrict__ bm,
    const float* __restrict__ Ws, const float* __restrict__ bs,
    float* __restrict__ out, int N, int B)
{
    const int b = blockIdx.x;
    const int tid = threadIdx.x;
    const int s = tid >> 6;
    const int lane = tid & 63;
    __shared__ float sf[8];

    const u64* src = chunkTop + ((size_t)(s * B + b)) * (CNK * KSEL); // 320 keys
    u64 v0 = src[lane];
    u64 v1 = src[lane + 64];
    u64 v2 = src[lane + 128];
    u64 v3 = src[lane + 192];
    u64 v4 = src[lane + 256];
    u64 keep = INF64;
    for (int r = 0; r < KSEL; ++r) {
        u64 cm = umin64(umin64(umin64(v0, v1), umin64(v2, v3)), v4);
#pragma unroll
        for (int o = 32; o; o >>= 1) cm = umin64(cm, __shfl_xor(cm, o, 64));
        if (v0 == cm) v0 = INF64;
        if (v1 == cm) v1 = INF64;
        if (v2 == cm) v2 = INF64;
        if (v3 == cm) v3 = INF64;
        if (v4 == cm) v4 = INF64;
        if (lane == r) keep = cm;
    }
    float w = 0.f, sv = 0.f;
    if (lane < KSEL) {
        float d2 = __uint_as_float((unsigned int)(keep >> 32));
        int j = (int)(unsigned int)(keep & 0xFFFFFFFFULL);
        float sim = sqrtf(d2) + 0.001f;
        w = expf(-sim);
        const float* __restrict__ rctx = s ? rctx1 : rctx0;
        sv = rctx[(size_t)b * N + j];
    }
    float sw = w, ssw = sv * w, ss = sv, ss2 = sv * sv;
#pragma unroll
    for (int o = 32; o; o >>= 1) {
        sw  += __shfl_down(sw,  o, 64);
        ssw += __shfl_down(ssw, o, 64);
        ss  += __shfl_down(ss,  o, 64);
        ss2 += __shfl_down(ss2, o, 64);
    }
    if (lane == 0) {
        sf[0 + s] = sw;
        sf[2 + s] = ssw / sw;
        float mean = ss * (1.f / KSEL);
        float var = (ss2 - (float)KSEL * mean * mean) * (1.f / (KSEL - 1));
        sf[4 + s] = sqrtf(fmaxf(var, 0.f));
        if (s == 0) { sf[6] = mean_in[b]; sf[7] = std_in[b]; }
    }
    __syncthreads();

    if (tid < 64) {
        float f0 = sf[0], f1 = sf[1], f2 = sf[2], f3 = sf[3];
        float f4 = sf[4], f5 = sf[5], f6 = sf[6], f7 = sf[7];
        float h = b1[lane];
        h = fmaf(f0, W1[0 * 64 + lane], h);
        h = fmaf(f1, W1[1 * 64 + lane], h);
        h = fmaf(f2, W1[2 * 64 + lane], h);
        h = fmaf(f3, W1[3 * 64 + lane], h);
        h = fmaf(f4, W1[4 * 64 + lane], h);
        h = fmaf(f5, W1[5 * 64 + lane], h);
        h = fmaf(f6, W1[6 * 64 + lane], h);
        h = fmaf(f7, W1[7 * 64 + lane], h);
        h = fmaxf(h, 0.f);
        float mo = h * Wm[lane], so = h * Ws[lane];
#pragma unroll
        for (int o = 32; o; o >>= 1) {
            mo += __shfl_down(mo, o, 64);
            so += __shfl_down(so, o, 64);
        }
        if (lane == 0) {
            out[b] = mo + bm[0];
            out[B + b] = so + bs[0];
        }
    }
}

extern "C" void kernel_launch(void* const* d_in, const int* in_sizes, int n_in,
                              void* d_out, int out_size, void* d_ws, size_t ws_size,
                              hipStream_t stream) {
    const float* emb0    = (const float*)d_in[0];
    const float* emb1    = (const float*)d_in[1];
    const float* rctx0   = (const float*)d_in[2];
    const float* rctx1   = (const float*)d_in[3];
    const int*   idx0    = (const int*)d_in[4];
    const int*   idx1    = (const int*)d_in[5];
    const float* mean_in = (const float*)d_in[6];
    const float* std_in  = (const float*)d_in[7];
    const float* W1      = (const float*)d_in[8];
    const float* b1      = (const float*)d_in[9];
    const float* Wm      = (const float*)d_in[10];
    const float* bm      = (const float*)d_in[11];
    const float* Ws      = (const float*)d_in[12];
    const float* bs      = (const float*)d_in[13];

    const int B = in_sizes[4];          // 512
    const int N = in_sizes[0] / 16;     // 50000

    int chlen = (((N + CNK - 1) / CNK) + 31) & ~31;   // 3136, multiple of 32
    int npad  = chlen * CNK;                          // 50176

    float* neBuf = (float*)d_ws;                                   // [2][npad] = 401 KB
    u64* chunkTop = (u64*)((char*)d_ws + (size_t)2 * npad * sizeof(float)); // 2.62 MB

    norm_kernel<<<dim3(npad / 256, 2), 256, 0, stream>>>(emb0, emb1, neBuf, N, npad);

    knn_scan_kernel<<<dim3(2 * (B / QT) * CNK), NTHR, 0, stream>>>(
        emb0, emb1, idx0, idx1, neBuf, chunkTop, N, B, chlen);

    merge_mlp_kernel<<<dim3(B), 128, 0, stream>>>(
        chunkTop, rctx0, rctx1, mean_in, std_in,
        W1, b1, Wm, bm, Ws, bs, (float*)d_out, N, B);
}

// Round 2
// 259.497 us; speedup vs baseline: 1.1984x; 1.1984x over previous
//
#include <hip/hip_runtime.h>
#include <math.h>

typedef unsigned long long u64;
typedef unsigned int u32;
#define INF64 0xFFFFFFFFFFFFFFFFULL
#define FBIG 3.3e38f
#define KSEL 20
#define QT   32      // queries per block = MFMA N dim
#define CNK  16      // chunks per side
#define CAP  256     // survivor buffer per query (typ ~64 with 21-of-1024 bound)
#define PREFT 4      // prefix tiles per wave (8 waves * 4 * 32 rows = 1024-row sample)
#define DEPS 0.5f    // 2*eps bound slack; worst-case |approx-exact| d2 err ~0.18
#define NTHR 512

typedef __bf16 bf16x8 __attribute__((ext_vector_type(8)));
typedef float  f32x16 __attribute__((ext_vector_type(16)));
typedef unsigned int uint4e __attribute__((ext_vector_type(4)));

static __device__ __forceinline__ u32 asu(float f) { return __builtin_bit_cast(u32, f); }
static __device__ __forceinline__ float trunchi(u32 u) { return __builtin_bit_cast(float, u & 0xffff0000u); }
#define PERM2(a,b) __builtin_amdgcn_perm((a),(b),0x07060302u)
static __device__ __forceinline__ bf16x8 mk8(u32 a, u32 b, u32 c, u32 d) {
    uint4e t = {a, b, c, d};
    return __builtin_bit_cast(bf16x8, t);
}
static __device__ __forceinline__ f32x16 zero16() {
    f32x16 z = {0.f,0.f,0.f,0.f,0.f,0.f,0.f,0.f,0.f,0.f,0.f,0.f,0.f,0.f,0.f,0.f};
    return z;
}

static __device__ __forceinline__ float dot16(
    float4 a0, float4 a1, float4 a2, float4 a3,
    float4 b0, float4 b1, float4 b2, float4 b3)
{
    float d = 0.f;
    d = fmaf(a0.x, b0.x, d); d = fmaf(a0.y, b0.y, d);
    d = fmaf(a0.z, b0.z, d); d = fmaf(a0.w, b0.w, d);
    d = fmaf(a1.x, b1.x, d); d = fmaf(a1.y, b1.y, d);
    d = fmaf(a1.z, b1.z, d); d = fmaf(a1.w, b1.w, d);
    d = fmaf(a2.x, b2.x, d); d = fmaf(a2.y, b2.y, d);
    d = fmaf(a2.z, b2.z, d); d = fmaf(a2.w, b2.w, d);
    d = fmaf(a3.x, b3.x, d); d = fmaf(a3.y, b3.y, d);
    d = fmaf(a3.z, b3.z, d); d = fmaf(a3.w, b3.w, d);
    return d;
}

// split 8 floats into bf16-hi (truncation) and bf16-lo (residual, truncated) frags
static __device__ __forceinline__ void cvt_hilo(float4 f0, float4 f1, bf16x8& hi, bf16x8& lo) {
    u32 u0=asu(f0.x),u1=asu(f0.y),u2=asu(f0.z),u3=asu(f0.w);
    u32 u4=asu(f1.x),u5=asu(f1.y),u6=asu(f1.z),u7=asu(f1.w);
    hi = mk8(PERM2(u1,u0), PERM2(u3,u2), PERM2(u5,u4), PERM2(u7,u6));
    u32 w0=asu(f0.x-trunchi(u0)), w1=asu(f0.y-trunchi(u1));
    u32 w2=asu(f0.z-trunchi(u2)), w3=asu(f0.w-trunchi(u3));
    u32 w4=asu(f1.x-trunchi(u4)), w5=asu(f1.y-trunchi(u5));
    u32 w6=asu(f1.z-trunchi(u6)), w7=asu(f1.w-trunchi(u7));
    lo = mk8(PERM2(w1,w0), PERM2(w3,w2), PERM2(w5,w4), PERM2(w7,w6));
}

// one 32-row x 32-query tile: qe[row][q] ~= Q.E^T via 3 chained MFMAs (hi*hi+hi*lo+lo*hi)
static __device__ __forceinline__ f32x16 tile_qe(
    const float* __restrict__ embS, int base, int col, int kb, int N,
    bf16x8 B1, bf16x8 B2)
{
    int row = base + col;
    row = min(row, N - 1);                       // OOB rows: ne-pad (FBIG) filters them
    const float4* ep = (const float4*)(embS + (size_t)row * 16 + kb * 8);
    float4 f0 = ep[0], f1 = ep[1];
    bf16x8 A1, A2;
    cvt_hilo(f0, f1, A1, A2);
    f32x16 acc = zero16();
    acc = __builtin_amdgcn_mfma_f32_32x32x16_bf16(A1, B1, acc, 0, 0, 0);
    acc = __builtin_amdgcn_mfma_f32_32x32x16_bf16(A1, B2, acc, 0, 0, 0);
    acc = __builtin_amdgcn_mfma_f32_32x32x16_bf16(A2, B1, acc, 0, 0, 0);
    return acc;
}

// per-row squared norms, padded with FBIG past N (self-filtering ragged tiles)
__global__ __launch_bounds__(256) void norm_kernel(
    const float* __restrict__ emb0, const float* __restrict__ emb1,
    float* __restrict__ neBuf, int N, int npad)
{
    const int j = blockIdx.x * 256 + threadIdx.x;
    const float* __restrict__ e = blockIdx.y ? emb1 : emb0;
    float* __restrict__ o = neBuf + (size_t)blockIdx.y * npad;
    float v = FBIG;
    if (j < N) {
        const float4* p = (const float4*)(e + (size_t)j * 16);
        float4 e0=p[0],e1=p[1],e2=p[2],e3=p[3];
        v = dot16(e0,e1,e2,e3, e0,e1,e2,e3);
    }
    if (j < npad) o[j] = v;
}

// Kernel A: per (side, 32-query tile, chunk). MFMA approximate filter + exact refine.
// Selection phases use ballot/popcount radix-select (scalar threshold build) --
// NO cross-lane shfl chains (those ds_swizzle chains were the 111us latency floor).
__global__ __launch_bounds__(NTHR, 4) void knn_scan_kernel(
    const float* __restrict__ emb0, const float* __restrict__ emb1,
    const int* __restrict__ idx0, const int* __restrict__ idx1,
    const float* __restrict__ neBuf,
    u64* __restrict__ chunkTop, int N, int B, int chlen)
{
    const int tid  = threadIdx.x;
    const int lane = tid & 63;
    const int wv   = tid >> 6;          // 0..7
    const int col  = lane & 31;         // query column
    const int kb   = lane >> 5;         // k-half / row-group bit
    const int bx   = blockIdx.x;
    const int xcd  = bx & 7;            // XCD swizzle: even XCDs side 0, odd side 1
    const int s    = xcd & 1;
    const int t_   = (bx >> 3) * 4 + (xcd >> 1);
    const int c    = t_ & (CNK - 1);
    const int qt   = t_ >> 4;
    const int qbase = qt * QT;
    const int jbeg = c * chlen;
    const int tpc  = chlen >> 5;        // 32-row tiles per chunk
    const int npad = chlen * CNK;

    const float* __restrict__ embS = s ? emb1 : emb0;
    const int*   __restrict__ idxp = s ? idx1 : idx0;
    const float* __restrict__ neS  = neBuf + (size_t)s * npad;

    __shared__ float Qs[QT][16];
    __shared__ float naS[QT];
    __shared__ int   sq[QT];
    __shared__ int   scnt[QT];
    __shared__ float sthr[QT];
    __shared__ float sMin[QT][32];
    __shared__ u32   sbuf[QT][CAP];

    if (tid < QT) { sq[tid] = idxp[qbase + tid]; scnt[tid] = 0; }
    __syncthreads();
    if (tid < 128) {
        int q = tid >> 2, part = tid & 3;
        ((float4*)(&Qs[q][0]))[part] = ((const float4*)(embS + (size_t)sq[q] * 16))[part];
    }
    __syncthreads();
    if (tid < QT) {
        const float4* qp = (const float4*)(&Qs[tid][0]);
        float4 a0=qp[0],a1=qp[1],a2=qp[2],a3=qp[3];
        naS[tid] = dot16(a0,a1,a2,a3, a0,a1,a2,a3);
    }
    // B fragments: this lane's 8 k-elements of query col (hi and lo parts)
    bf16x8 B1, B2;
    {
        const float4* qp = (const float4*)(&Qs[col][kb * 8]);
        float4 f0 = qp[0], f1 = qp[1];
        cvt_hilo(f0, f1, B1, B2);
    }
    __syncthreads();

    const float na_l  = naS[col];
    const int   self_l = sq[col];

    // ---- prefix sample: 2-smallest approx-d2 per lane over 4 tiles (128 rows/lane)
    float m0v = FBIG, m1v = FBIG;
#define PINS(r, nef) { float v_ = fmaf(acc[r], -2.f, na_l + (nef)); \
    float t1_ = fminf(m1v, fmaxf(m0v, v_)); m0v = fminf(m0v, v_); m1v = t1_; }
    for (int pt = 0; pt < PREFT; ++pt) {
        const int t = wv + pt * 8;
        const int base = jbeg + t * 32;
        const float4* np_ = (const float4*)(neS + base + kb * 4);
        float4 n0 = np_[0], n1 = np_[2], n2 = np_[4], n3 = np_[6];
        f32x16 acc = tile_qe(embS, base, col, kb, N, B1, B2);
        PINS(0,n0.x)  PINS(1,n0.y)  PINS(2,n0.z)  PINS(3,n0.w)
        PINS(4,n1.x)  PINS(5,n1.y)  PINS(6,n1.z)  PINS(7,n1.w)
        PINS(8,n2.x)  PINS(9,n2.y)  PINS(10,n2.z) PINS(11,n2.w)
        PINS(12,n3.x) PINS(13,n3.y) PINS(14,n3.z) PINS(15,n3.w)
    }
#undef PINS
    // clamp >=0 so the u32 bit pattern is order-monotone for radix select
    sMin[col][(wv * 2 + kb) * 2 + 0] = fmaxf(m0v, 0.f);
    sMin[col][(wv * 2 + kb) * 2 + 1] = fmaxf(m1v, 0.f);
    __syncthreads();

    // ---- wave wv: 21st-smallest of its 4 queries' 32 sampled mins = filter bound.
    // Ballot radix-select on f32 bits: smallest T with count(v <= T) >= 21.
    for (int qq = 0; qq < 4; ++qq) {
        const int q = wv * 4 + qq;
        const u32 vb = (lane < 32) ? asu(sMin[q][lane]) : 0xFFFFFFFFu;
        u32 T = 0;
        for (int bb = 30; bb >= 0; --bb) {
            u32 U = T | ((1u << bb) - 1u);
            int nle = __popcll(__ballot(vb <= U));
            if (nle < KSEL + 1) T |= (1u << bb);
        }
        if (lane == 0) sthr[q] = __uint_as_float(T) + DEPS;
    }
    __syncthreads();
    const float thr_l = sthr[col];

    // ---- main filtered scan over all tiles of the chunk
#define EPI(r, nef) { float ad_ = fmaf(acc[r], -2.f, na_l + (nef)); \
    if (ad_ <= thr_l) msk |= (1u << (r)); }
    for (int t = wv; t < tpc; t += 8) {
        const int base = jbeg + t * 32;
        const float4* np_ = (const float4*)(neS + base + kb * 4);
        float4 n0 = np_[0], n1 = np_[2], n2 = np_[4], n3 = np_[6];
        f32x16 acc = tile_qe(embS, base, col, kb, N, B1, B2);
        u32 msk = 0;
        EPI(0,n0.x)  EPI(1,n0.y)  EPI(2,n0.z)  EPI(3,n0.w)
        EPI(4,n1.x)  EPI(5,n1.y)  EPI(6,n1.z)  EPI(7,n1.w)
        EPI(8,n2.x)  EPI(9,n2.y)  EPI(10,n2.z) EPI(11,n2.w)
        EPI(12,n3.x) EPI(13,n3.y) EPI(14,n3.z) EPI(15,n3.w)
        while (msk) {
            int r = __ffs(msk) - 1;
            msk &= msk - 1;
            int j = base + (r & 3) + 8 * (r >> 2) + 4 * kb;
            if (j != self_l) {
                int sl = atomicAdd(&scnt[col], 1);
                if (sl < CAP) sbuf[col][sl] = (u32)j;
            }
        }
    }
#undef EPI
    __syncthreads();

    // ---- exact refine (bit-identical fp32 dot16 path; ne from neBuf is the
    // same dot16 on the same data) + radix top-20 per query.
    for (int qq = 0; qq < 4; ++qq) {
        const int q = wv * 4 + qq;
        const int M = min(scnt[q], CAP);
        const float4* qp = (const float4*)(&Qs[q][0]);
        const float4 q0=qp[0], q1=qp[1], q2=qp[2], q3=qp[3];
        const float naq = naS[q];
        auto rk = [&](int i) -> u64 {
            int j = (int)sbuf[q][i];
            const float4* p = (const float4*)(embS + (size_t)j * 16);
            float4 e0=p[0],e1=p[1],e2=p[2],e3=p[3];
            float qe  = dot16(q0,q1,q2,q3, e0,e1,e2,e3);
            float dd  = fmaxf(fmaf(qe, -2.f, naq + neS[j]), 0.f);
            return ((u64)asu(dd) << 32) | (u32)j;
        };
        u64 k0 = (lane < M)       ? rk(lane)       : INF64;
        u64 k1 = (lane + 64 < M)  ? rk(lane + 64)  : INF64;
        u64 k2 = (lane + 128 < M) ? rk(lane + 128) : INF64;
        u64 k3 = (lane + 192 < M) ? rk(lane + 192) : INF64;
        // radix-select exact 20th-smallest key. Keys unique (j in low bits).
        // Meaningful bits: 63..32 (d2) and 15..0 (j < 65536); 31..16 always 0.
        u64 T = 0;
        for (int bb = 63; bb >= 32; --bb) {
            u64 U = T | ((1ull << bb) - 1ull);
            int nle = __popcll(__ballot(k0 <= U)) + __popcll(__ballot(k1 <= U))
                    + __popcll(__ballot(k2 <= U)) + __popcll(__ballot(k3 <= U));
            if (nle < KSEL) T |= (1ull << bb);
        }
        for (int bb = 15; bb >= 0; --bb) {
            u64 U = T | ((1ull << bb) - 1ull);
            int nle = __popcll(__ballot(k0 <= U)) + __popcll(__ballot(k1 <= U))
                    + __popcll(__ballot(k2 <= U)) + __popcll(__ballot(k3 <= U));
            if (nle < KSEL) T |= (1ull << bb);
        }
        // ballot-prefix compaction: write the (exactly 20) keys <= T, unordered
        u64* dst = chunkTop + ((size_t)(s * B + qbase + q) * CNK + c) * KSEL;
        int basec = 0;
        {
            u64 mm = __ballot(k0 <= T);
            if (k0 <= T) { int sl = basec + __popcll(mm & ((1ull << lane) - 1ull)); if (sl < KSEL) dst[sl] = k0; }
            basec += __popcll(mm);
        }
        {
            u64 mm = __ballot(k1 <= T);
            if (k1 <= T) { int sl = basec + __popcll(mm & ((1ull << lane) - 1ull)); if (sl < KSEL) dst[sl] = k1; }
            basec += __popcll(mm);
        }
        {
            u64 mm = __ballot(k2 <= T);
            if (k2 <= T) { int sl = basec + __popcll(mm & ((1ull << lane) - 1ull)); if (sl < KSEL) dst[sl] = k2; }
            basec += __popcll(mm);
        }
        {
            u64 mm = __ballot(k3 <= T);
            if (k3 <= T) { int sl = basec + __popcll(mm & ((1ull << lane) - 1ull)); if (sl < KSEL) dst[sl] = k3; }
            basec += __popcll(mm);
        }
        // defensive: pad unwritten slots (only possible in degenerate M<20 case)
        for (int sl = basec + lane; sl < KSEL; sl += 64) dst[sl] = INF64;
    }
}

// Kernel B: per row b: wave s radix-selects the 20th-smallest of its side's
// 320 chunk keys, accumulates f1/f2/f3 sums in place, then fused MLP.
__global__ __launch_bounds__(128) void merge_mlp_kernel(
    const u64* __restrict__ chunkTop,
    const float* __restrict__ rctx0, const float* __restrict__ rctx1,
    const float* __restrict__ mean_in, const float* __restrict__ std_in,
    const float* __restrict__ W1, const float* __restrict__ b1,
    const float* __restrict__ Wm, const float* __restrict__ bm,
    const float* __restrict__ Ws, const float* __restrict__ bs,
    float* __restrict__ out, int N, int B)
{
    const int b = blockIdx.x;
    const int tid = threadIdx.x;
    const int s = tid >> 6;
    const int lane = tid & 63;
    __shared__ float sf[8];

    const u64* src = chunkTop + ((size_t)(s * B + b)) * (CNK * KSEL); // 320 keys
    u64 v0 = src[lane];
    u64 v1 = src[lane + 64];
    u64 v2 = src[lane + 128];
    u64 v3 = src[lane + 192];
    u64 v4 = src[lane + 256];
    u64 T = 0;
    for (int bb = 63; bb >= 32; --bb) {
        u64 U = T | ((1ull << bb) - 1ull);
        int nle = __popcll(__ballot(v0 <= U)) + __popcll(__ballot(v1 <= U))
                + __popcll(__ballot(v2 <= U)) + __popcll(__ballot(v3 <= U))
                + __popcll(__ballot(v4 <= U));
        if (nle < KSEL) T |= (1ull << bb);
    }
    for (int bb = 15; bb >= 0; --bb) {
        u64 U = T | ((1ull << bb) - 1ull);
        int nle = __popcll(__ballot(v0 <= U)) + __popcll(__ballot(v1 <= U))
                + __popcll(__ballot(v2 <= U)) + __popcll(__ballot(v3 <= U))
                + __popcll(__ballot(v4 <= U));
        if (nle < KSEL) T |= (1ull << bb);
    }
    const float* __restrict__ rctx = s ? rctx1 : rctx0;
    float sw = 0.f, ssw = 0.f, ss = 0.f, ss2 = 0.f;
#define ACC(vx) if (vx <= T && vx != INF64) { \
        float d2 = __uint_as_float((u32)((vx) >> 32)); \
        int j = (int)(u32)((vx) & 0xFFFFFFFFULL); \
        float sim = sqrtf(d2) + 0.001f; \
        float wr = expf(-sim); \
        float svr = rctx[(size_t)b * N + j]; \
        sw += wr; ssw += svr * wr; ss += svr; ss2 += svr * svr; }
    ACC(v0) ACC(v1) ACC(v2) ACC(v3) ACC(v4)
#undef ACC
#pragma unroll
    for (int o = 32; o; o >>= 1) {
        sw  += __shfl_down(sw,  o, 64);
        ssw += __shfl_down(ssw, o, 64);
        ss  += __shfl_down(ss,  o, 64);
        ss2 += __shfl_down(ss2, o, 64);
    }
    if (lane == 0) {
        sf[0 + s] = sw;
        sf[2 + s] = ssw / sw;
        float mean = ss * (1.f / KSEL);
        float var = (ss2 - (float)KSEL * mean * mean) * (1.f / (KSEL - 1));
        sf[4 + s] = sqrtf(fmaxf(var, 0.f));
        if (s == 0) { sf[6] = mean_in[b]; sf[7] = std_in[b]; }
    }
    __syncthreads();

    if (tid < 64) {
        float f0 = sf[0], f1 = sf[1], f2 = sf[2], f3 = sf[3];
        float f4 = sf[4], f5 = sf[5], f6 = sf[6], f7 = sf[7];
        float h = b1[lane];
        h = fmaf(f0, W1[0 * 64 + lane], h);
        h = fmaf(f1, W1[1 * 64 + lane], h);
        h = fmaf(f2, W1[2 * 64 + lane], h);
        h = fmaf(f3, W1[3 * 64 + lane], h);
        h = fmaf(f4, W1[4 * 64 + lane], h);
        h = fmaf(f5, W1[5 * 64 + lane], h);
        h = fmaf(f6, W1[6 * 64 + lane], h);
        h = fmaf(f7, W1[7 * 64 + lane], h);
        h = fmaxf(h, 0.f);
        float mo = h * Wm[lane], so = h * Ws[lane];
#pragma unroll
        for (int o = 32; o; o >>= 1) {
            mo += __shfl_down(mo, o, 64);
            so += __shfl_down(so, o, 64);
        }
        if (lane == 0) {
            out[b] = mo + bm[0];
            out[B + b] = so + bs[0];
        }
    }
}

extern "C" void kernel_launch(void* const* d_in, const int* in_sizes, int n_in,
                              void* d_out, int out_size, void* d_ws, size_t ws_size,
                              hipStream_t stream) {
    const float* emb0    = (const float*)d_in[0];
    const float* emb1    = (const float*)d_in[1];
    const float* rctx0   = (const float*)d_in[2];
    const float* rctx1   = (const float*)d_in[3];
    const int*   idx0    = (const int*)d_in[4];
    const int*   idx1    = (const int*)d_in[5];
    const float* mean_in = (const float*)d_in[6];
    const float* std_in  = (const float*)d_in[7];
    const float* W1      = (const float*)d_in[8];
    const float* b1      = (const float*)d_in[9];
    const float* Wm      = (const float*)d_in[10];
    const float* bm      = (const float*)d_in[11];
    const float* Ws      = (const float*)d_in[12];
    const float* bs      = (const float*)d_in[13];

    const int B = in_sizes[4];          // 512
    const int N = in_sizes[0] / 16;     // 50000

    int chlen = (((N + CNK - 1) / CNK) + 31) & ~31;   // 3136, multiple of 32
    int npad  = chlen * CNK;                          // 50176

    float* neBuf = (float*)d_ws;                                   // [2][npad] = 401 KB
    u64* chunkTop = (u64*)((char*)d_ws + (size_t)2 * npad * sizeof(float)); // 2.62 MB

    norm_kernel<<<dim3(npad / 256, 2), 256, 0, stream>>>(emb0, emb1, neBuf, N, npad);

    knn_scan_kernel<<<dim3(2 * (B / QT) * CNK), NTHR, 0, stream>>>(
        emb0, emb1, idx0, idx1, neBuf, chunkTop, N, B, chlen);

    merge_mlp_kernel<<<dim3(B), 128, 0, stream>>>(
        chunkTop, rctx0, rctx1, mean_in, std_in,
        W1, b1, Wm, bm, Ws, bs, (float*)d_out, N, B);
}